// Round 4
// baseline (285.952 us; speedup 1.0000x reference)
//
#include <hip/hip_runtime.h>
#include <math.h>

#define Hd 128
#define Wd 128
#define HW 16384

__device__ __forceinline__ float wred(float v) {
  #pragma unroll
  for (int o = 32; o > 0; o >>= 1) v += __shfl_down(v, o, 64);
  return v;
}

// ---- K1: grouped 3x3 key conv + ReLU. grid (8,4,64), block 256; 2 vertical px/thread
// z = b*8+g. Tile 16w x 32h, halo 34x18 in LDS rows padded to 24 (exact 2-way banks).
__global__ __launch_bounds__(256) void k_keyconv(const float* __restrict__ x,
                                                 const float* __restrict__ wkey,
                                                 float* __restrict__ kout) {
  __shared__ float xt[8][34][24];
  const int tid = threadIdx.x;
  const int tx = tid & 15, ty = tid >> 4;  // ty 0..15 -> rows 2ty, 2ty+1
  const int b = blockIdx.z >> 3, g = blockIdx.z & 7;
  const int h0 = blockIdx.y * 32, w0 = blockIdx.x * 16;
  for (int i = tid; i < 8 * 612; i += 256) {
    int ch = i / 612, r = i - ch * 612;
    int yy = r / 18, xx = r - yy * 18;
    int gh = h0 + yy - 1, gw = w0 + xx - 1;
    float v = 0.f;
    if (gh >= 0 && gh < Hd && gw >= 0 && gw < Wd)
      v = x[((long)(b * 64 + g * 8 + ch) << 14) + (gh << 7) + gw];
    xt[ch][yy][xx] = v;
  }
  __syncthreads();
  float acc0[8] = {0.f, 0.f, 0.f, 0.f, 0.f, 0.f, 0.f, 0.f};
  float acc1[8] = {0.f, 0.f, 0.f, 0.f, 0.f, 0.f, 0.f, 0.f};
  const float* wg = wkey + g * 576;
  #pragma unroll
  for (int ich = 0; ich < 8; ++ich) {
    float nb[12];  // input rows 2ty-1 .. 2ty+2 -> xt rows 2ty..2ty+3, cols tx..tx+2
    #pragma unroll
    for (int rr = 0; rr < 4; ++rr)
      #pragma unroll
      for (int cc = 0; cc < 3; ++cc)
        nb[rr * 3 + cc] = xt[ich][2 * ty + rr][tx + cc];
    #pragma unroll
    for (int oc = 0; oc < 8; ++oc) {
      const float* wr = wg + oc * 72 + ich * 9;  // wave-uniform -> scalar loads
      #pragma unroll
      for (int dy = 0; dy < 3; ++dy)
        #pragma unroll
        for (int dx = 0; dx < 3; ++dx) {
          float wv = wr[dy * 3 + dx];
          acc0[oc] += wv * nb[dy * 3 + dx];
          acc1[oc] += wv * nb[(dy + 1) * 3 + dx];
        }
    }
  }
  const int h = h0 + 2 * ty, w = w0 + tx;
  #pragma unroll
  for (int oc = 0; oc < 8; ++oc) {
    const long base = ((long)(b * 64 + g * 8 + oc) << 14);
    kout[base + (h << 7) + w] = fmaxf(acc0[oc], 0.f);
    kout[base + ((h + 1) << 7) + w] = fmaxf(acc1[oc], 0.f);
  }
}

// ---- K2: pointwise e1+e2 + c1 + GN partials. grid (128, B, 2), block 256 ----
// Block covers 128 pixels x 2 channel-halves (half = tid>>7). Both halves load all
// xc/kc (e1 needs them); __syncthreads() after loads makes in-place xv-over-k safe.
// Half h computes: c1 outs [16h,16h+16), full e1 (recompute), e2 gl in {2h,2h+1}.
__global__ __launch_bounds__(256) void k_embed(const float* __restrict__ x,
                                               float* __restrict__ kxv,
                                               const float* __restrict__ we1,
                                               const float* __restrict__ we2,
                                               const float* __restrict__ be2,
                                               const float* __restrict__ wc1,
                                               float* __restrict__ wpre,
                                               float* __restrict__ spart) {
  const int tid = threadIdx.x;
  const int half = tid >> 7;
  const int q = tid & 127;
  const int p = blockIdx.x * 128 + q;
  const int b = blockIdx.y;
  const int s = blockIdx.z;
  float xc[32], kc[32];
  #pragma unroll
  for (int j = 0; j < 32; ++j) {
    xc[j] = x[((long)(b * 64 + 32 * s + j) << 14) + p];
    kc[j] = kxv[((long)(b * 64 + 32 * s + j) << 14) + p];
  }
  __syncthreads();  // all kc reads complete before any c1 store (in-place safety)
  // c1 half: 16 outputs
  #pragma unroll 4
  for (int oo = 0; oo < 16; ++oo) {
    const int o = 16 * half + oo;
    const float* wr = wc1 + (32 * s + o) * 32;
    float a = 0.f;
    #pragma unroll
    for (int j = 0; j < 32; ++j) a += wr[j] * xc[j];
    kxv[((long)(b * 64 + 32 * s + o) << 14) + p] = a;
  }
  // e1 full (recomputed in both halves)
  float w1a[16];
  #pragma unroll
  for (int o = 0; o < 16; ++o) {
    const float* wr = we1 + (16 * s + o) * 64;
    float a = 0.f;
    #pragma unroll
    for (int j = 0; j < 32; ++j) a += wr[2 * j] * xc[j] + wr[2 * j + 1] * kc[j];
    w1a[o] = fmaxf(a, 0.f);
  }
  // e2 half: gl in {2*half, 2*half+1}
  const int row = blockIdx.x * 2 + ((tid >> 6) & 1);  // pixel-group id, [0,256)
  #pragma unroll
  for (int gi = 0; gi < 2; ++gi) {
    const int gl = 2 * half + gi;
    float lgs = 0.f, lgq = 0.f;
    #pragma unroll
    for (int kk = 0; kk < 9; ++kk) {
      const int oc2 = 36 * s + gl * 9 + kk;
      const float* wr = we2 + oc2 * 16;
      float a = be2[oc2];
      #pragma unroll
      for (int ic = 0; ic < 16; ++ic) a += wr[ic] * w1a[ic];
      wpre[((long)(b * 72 + oc2) << 14) + p] = a;
      lgs += a;
      lgq += a * a;
    }
    float r1 = wred(lgs), r2 = wred(lgq);
    if ((tid & 63) == 0) {
      spart[row * 128 + (b * 8 + 4 * s + gl) * 2 + 0] = r1;
      spart[row * 128 + (b * 8 + 4 * s + gl) * 2 + 1] = r2;
    }
  }
}

// ---- K3: reduce spart columns + finalize GN stats. 1 block x 128 threads ----
__global__ void k_gnstat(const float* __restrict__ spart, float* __restrict__ minv) {
  __shared__ float sred[128];
  const int t = threadIdx.x;  // 128
  float a = 0.f;
  #pragma unroll 8
  for (int r = 0; r < 256; ++r) a += spart[r * 128 + t];
  sred[t] = a;
  __syncthreads();
  if (t < 64) {
    const float N = 9.f * (float)HW;
    float s = sred[2 * t], q = sred[2 * t + 1];
    float m = s / N;
    float var = q / N - m * m;
    minv[2 * t] = m;
    minv[2 * t + 1] = rsqrtf(var + 1e-5f);
  }
}

// ---- K4: per-pixel local 3x3 conv + CA partials. grid (8,4,64), 2 vertical px/thread
// part layout: [row=128][ch=512], row = (by*8+bx)*4 + wave.
__global__ __launch_bounds__(256) void k_local(const float* __restrict__ kxv,
                                               const float* __restrict__ wpre,
                                               const float* __restrict__ minv,
                                               const float* __restrict__ gnw,
                                               const float* __restrict__ gnb,
                                               float* __restrict__ out,
                                               float* __restrict__ part) {
  __shared__ float xt[8][34][24];
  const int tid = threadIdx.x;
  const int tx = tid & 15, ty = tid >> 4;
  const int z = blockIdx.z;
  const int b2 = z >> 2, g = z & 3;
  const int t = b2 & 1, b = b2 >> 1;
  const int h0 = blockIdx.y * 32, w0 = blockIdx.x * 16;
  for (int i = tid; i < 8 * 612; i += 256) {
    int ch = i / 612, r = i - ch * 612;
    int yy = r / 18, xx = r - yy * 18;
    int gh = h0 + yy - 1, gw = w0 + xx - 1;
    float v = 0.f;
    if (gh >= 0 && gh < Hd && gw >= 0 && gw < Wd)
      v = kxv[((long)(b2 * 32 + g * 8 + ch) << 14) + (gh << 7) + gw];
    xt[ch][yy][xx] = v;
  }
  __syncthreads();
  const int gg = 4 * t + g;
  const float m = minv[(b * 8 + gg) * 2];
  const float inv = minv[(b * 8 + gg) * 2 + 1];
  const int p0 = ((h0 + 2 * ty) << 7) + (w0 + tx);
  const int p1 = p0 + 128;
  float wn0[9], wn1[9];
  #pragma unroll
  for (int kk = 0; kk < 9; ++kk) {
    const int ch72 = 36 * t + 9 * g + kk;
    const long base = ((long)(b * 72 + ch72) << 14);
    const float sc = inv * gnw[ch72], sh = gnb[ch72] - m * inv * gnw[ch72];
    wn0[kk] = wpre[base + p0] * sc + sh;
    wn1[kk] = wpre[base + p1] * sc + sh;
  }
  const int prow = (blockIdx.y * 8 + blockIdx.x) * 4 + (tid >> 6);
  #pragma unroll
  for (int cc = 0; cc < 8; ++cc) {
    float nb[12];
    #pragma unroll
    for (int rr = 0; rr < 4; ++rr)
      #pragma unroll
      for (int ccol = 0; ccol < 3; ++ccol)
        nb[rr * 3 + ccol] = xt[cc][2 * ty + rr][tx + ccol];
    float o0 = 0.f, o1 = 0.f;
    #pragma unroll
    for (int dy = 0; dy < 3; ++dy)
      #pragma unroll
      for (int dx = 0; dx < 3; ++dx) {
        o0 += wn0[dy * 3 + dx] * nb[dy * 3 + dx];
        o1 += wn1[dy * 3 + dx] * nb[(dy + 1) * 3 + dx];
      }
    const int ch512 = b2 * 32 + g * 8 + cc;
    out[((long)ch512 << 14) + p0] = o0;
    out[((long)ch512 << 14) + p1] = o1;
    float os = wred(o0 + o1);
    if ((tid & 63) == 0) part[prow * 512 + ch512] = os;
  }
}

// ---- K5: reduce CA partials + SE MLP (64 -> 4 relu -> 64 sigmoid). 1 block x 512 ----
__global__ void k_ca(const float* __restrict__ part, const float* __restrict__ du1,
                     const float* __restrict__ du2, float* __restrict__ ys) {
  __shared__ float sy[8][64];
  __shared__ float sy4[8][4];
  const int tid = threadIdx.x;  // 512
  const int b = tid >> 6, c = tid & 63;
  float acc = 0.f;
  #pragma unroll 8
  for (int r = 0; r < 128; ++r) acc += part[r * 512 + tid];
  sy[b][c] = acc * (1.f / (float)HW);
  __syncthreads();
  if (tid < 32) {
    int bb = tid >> 2, j = tid & 3;
    float a = 0.f;
    for (int c2 = 0; c2 < 64; ++c2) a += sy[bb][c2] * du1[j * 64 + c2];
    sy4[bb][j] = fmaxf(a, 0.f);
  }
  __syncthreads();
  float z = 0.f;
  #pragma unroll
  for (int j = 0; j < 4; ++j) z += sy4[b][j] * du2[c * 4 + j];
  ys[tid] = 1.f / (1.f + expf(-z));
}

// ---- K6: scale output by channel-attention gate ----
__global__ __launch_bounds__(256) void k_scale(float* __restrict__ out,
                                               const float* __restrict__ ys) {
  const long i4 = (long)blockIdx.x * 256 + threadIdx.x;  // float4 index
  const long e = i4 * 4;
  const int bc = (int)(e >> 14);  // b*64+c
  const float s = ys[bc];
  float4* o = (float4*)out;
  float4 v = o[i4];
  v.x *= s; v.y *= s; v.z *= s; v.w *= s;
  o[i4] = v;
}

extern "C" void kernel_launch(void* const* d_in, const int* in_sizes, int n_in,
                              void* d_out, int out_size, void* d_ws, size_t ws_size,
                              hipStream_t stream) {
  const float* x    = (const float*)d_in[0];
  const float* wkey = (const float*)d_in[1];
  const float* we1  = (const float*)d_in[2];
  const float* we2  = (const float*)d_in[3];
  const float* be2  = (const float*)d_in[4];
  const float* gnw  = (const float*)d_in[5];
  const float* gnb  = (const float*)d_in[6];
  const float* wc1  = (const float*)d_in[7];
  const float* du1  = (const float*)d_in[8];
  const float* du2  = (const float*)d_in[9];
  float* out = (float*)d_out;
  float* ws = (float*)d_ws;

  float* kxv  = ws;                    // 8*64*HW floats (k, then xv in place)
  float* wpre = ws + 8388608;          // 8*72*HW floats
  float* part = ws + 17825792;         // spart [256][128] / part [128][512] overlay
  float* spart = part;                 //   (disjoint lifetimes)
  float* minv = part + 131072;         // 128 floats
  float* ys   = minv + 128;            // 512 floats

  k_keyconv<<<dim3(8, 4, 64), 256, 0, stream>>>(x, wkey, kxv);
  k_embed<<<dim3(128, 8, 2), 256, 0, stream>>>(x, kxv, we1, we2, be2, wc1, wpre, spart);
  k_gnstat<<<1, 128, 0, stream>>>(spart, minv);
  k_local<<<dim3(8, 4, 64), 256, 0, stream>>>(kxv, wpre, minv, gnw, gnb, out, part);
  k_ca<<<1, 512, 0, stream>>>(part, du1, du2, ys);
  k_scale<<<8192, 256, 0, stream>>>(out, ys);
}

// Round 5
// 285.066 us; speedup vs baseline: 1.0031x; 1.0031x over previous
//
#include <hip/hip_runtime.h>
#include <math.h>

#define Hd 128
#define Wd 128
#define HW 16384

__device__ __forceinline__ float wred(float v) {
  #pragma unroll
  for (int o = 32; o > 0; o >>= 1) v += __shfl_down(v, o, 64);
  return v;
}

// ---- K1: grouped 3x3 key conv + ReLU. grid (8,4,64), block 256; 2 vertical px/thread
// z = b*8+g. Tile 16w x 32h, halo 34x18 in LDS rows padded to 24 (exact 2-way banks).
__global__ __launch_bounds__(256) void k_keyconv(const float* __restrict__ x,
                                                 const float* __restrict__ wkey,
                                                 float* __restrict__ kout) {
  __shared__ float xt[8][34][24];
  const int tid = threadIdx.x;
  const int tx = tid & 15, ty = tid >> 4;  // ty 0..15 -> rows 2ty, 2ty+1
  const int b = blockIdx.z >> 3, g = blockIdx.z & 7;
  const int h0 = blockIdx.y * 32, w0 = blockIdx.x * 16;
  for (int i = tid; i < 8 * 612; i += 256) {
    int ch = i / 612, r = i - ch * 612;
    int yy = r / 18, xx = r - yy * 18;
    int gh = h0 + yy - 1, gw = w0 + xx - 1;
    float v = 0.f;
    if (gh >= 0 && gh < Hd && gw >= 0 && gw < Wd)
      v = x[((long)(b * 64 + g * 8 + ch) << 14) + (gh << 7) + gw];
    xt[ch][yy][xx] = v;
  }
  __syncthreads();
  float acc0[8] = {0.f, 0.f, 0.f, 0.f, 0.f, 0.f, 0.f, 0.f};
  float acc1[8] = {0.f, 0.f, 0.f, 0.f, 0.f, 0.f, 0.f, 0.f};
  const float* wg = wkey + g * 576;
  #pragma unroll
  for (int ich = 0; ich < 8; ++ich) {
    float nb[12];  // input rows 2ty-1 .. 2ty+2 -> xt rows 2ty..2ty+3, cols tx..tx+2
    #pragma unroll
    for (int rr = 0; rr < 4; ++rr)
      #pragma unroll
      for (int cc = 0; cc < 3; ++cc)
        nb[rr * 3 + cc] = xt[ich][2 * ty + rr][tx + cc];
    #pragma unroll
    for (int oc = 0; oc < 8; ++oc) {
      const float* wr = wg + oc * 72 + ich * 9;  // wave-uniform -> scalar loads
      #pragma unroll
      for (int dy = 0; dy < 3; ++dy)
        #pragma unroll
        for (int dx = 0; dx < 3; ++dx) {
          float wv = wr[dy * 3 + dx];
          acc0[oc] += wv * nb[dy * 3 + dx];
          acc1[oc] += wv * nb[(dy + 1) * 3 + dx];
        }
    }
  }
  const int h = h0 + 2 * ty, w = w0 + tx;
  #pragma unroll
  for (int oc = 0; oc < 8; ++oc) {
    const long base = ((long)(b * 64 + g * 8 + oc) << 14);
    kout[base + (h << 7) + w] = fmaxf(acc0[oc], 0.f);
    kout[base + ((h + 1) << 7) + w] = fmaxf(acc1[oc], 0.f);
  }
}

// ---- K2: pointwise e1+e2 + c1 + GN partials. grid (32, B, 2), block 256 ----
// 2 horizontal px/thread via float2: each weight dword feeds 2 FMAs (halved scalar
// fetch per FMA, 2x ILP). No barrier, no recompute. In-place xv-over-k: same thread
// reads kc then writes c1 at the same addresses (compiler keeps order: same pointer).
// spart layout: [row=128][col=128], row = bx*4+wave (per (b,s): 32 blk x 4 waves).
__global__ __launch_bounds__(256) void k_embed(const float* __restrict__ x,
                                               float* __restrict__ kxv,
                                               const float* __restrict__ we1,
                                               const float* __restrict__ we2,
                                               const float* __restrict__ be2,
                                               const float* __restrict__ wc1,
                                               float* __restrict__ wpre,
                                               float* __restrict__ spart) {
  const int tid = threadIdx.x;
  const int q = blockIdx.x * 256 + tid;  // float2 index within a channel plane [0,8192)
  const int b = blockIdx.y;
  const int s = blockIdx.z;
  const float2* x2 = (const float2*)x;
  float2* kxv2 = (float2*)kxv;
  float2* wpre2 = (float2*)wpre;
  float2 xc[32], kc[32];
  #pragma unroll
  for (int j = 0; j < 32; ++j) {
    xc[j] = x2[((long)(b * 64 + 32 * s + j) << 13) + q];
    kc[j] = kxv2[((long)(b * 64 + 32 * s + j) << 13) + q];
  }
  // value path: grouped 1x1 conv (32->32 per half), store xv over k slots
  #pragma unroll 4
  for (int o = 0; o < 32; ++o) {
    const float* wr = wc1 + (32 * s + o) * 32;
    float a0 = 0.f, a1 = 0.f;
    #pragma unroll
    for (int j = 0; j < 32; ++j) {
      float wv = wr[j];
      a0 += wv * xc[j].x;
      a1 += wv * xc[j].y;
    }
    float2 r; r.x = a0; r.y = a1;
    kxv2[((long)(b * 64 + 32 * s + o) << 13) + q] = r;
  }
  // e1: 64(interleaved x,k) -> 16, ReLU
  float2 w1a[16];
  #pragma unroll
  for (int o = 0; o < 16; ++o) {
    const float* wr = we1 + (16 * s + o) * 64;
    float a0 = 0.f, a1 = 0.f;
    #pragma unroll
    for (int j = 0; j < 32; ++j) {
      float w0 = wr[2 * j], w1 = wr[2 * j + 1];
      a0 += w0 * xc[j].x + w1 * kc[j].x;
      a1 += w0 * xc[j].y + w1 * kc[j].y;
    }
    w1a[o].x = fmaxf(a0, 0.f);
    w1a[o].y = fmaxf(a1, 0.f);
  }
  // e2: 16 -> 36 (+bias), store w_pre, per-wave GN sum/sumsq -> spart slot
  const int row = blockIdx.x * 4 + (tid >> 6);
  #pragma unroll
  for (int gl = 0; gl < 4; ++gl) {
    float lgs = 0.f, lgq = 0.f;
    #pragma unroll
    for (int kk = 0; kk < 9; ++kk) {
      const int oc2 = 36 * s + gl * 9 + kk;
      const float* wr = we2 + oc2 * 16;
      float a0 = be2[oc2], a1 = a0;
      #pragma unroll
      for (int ic = 0; ic < 16; ++ic) {
        float wv = wr[ic];
        a0 += wv * w1a[ic].x;
        a1 += wv * w1a[ic].y;
      }
      float2 r; r.x = a0; r.y = a1;
      wpre2[((long)(b * 72 + oc2) << 13) + q] = r;
      lgs += a0 + a1;
      lgq += a0 * a0 + a1 * a1;
    }
    float r1 = wred(lgs), r2 = wred(lgq);
    if ((tid & 63) == 0) {
      spart[row * 128 + (b * 8 + 4 * s + gl) * 2 + 0] = r1;
      spart[row * 128 + (b * 8 + 4 * s + gl) * 2 + 1] = r2;
    }
  }
}

// ---- K3: reduce spart columns + finalize GN stats. 1 block x 128 threads ----
__global__ void k_gnstat(const float* __restrict__ spart, float* __restrict__ minv) {
  __shared__ float sred[128];
  const int t = threadIdx.x;  // 128
  float a = 0.f;
  #pragma unroll 8
  for (int r = 0; r < 128; ++r) a += spart[r * 128 + t];
  sred[t] = a;
  __syncthreads();
  if (t < 64) {
    const float N = 9.f * (float)HW;
    float s = sred[2 * t], q = sred[2 * t + 1];
    float m = s / N;
    float var = q / N - m * m;
    minv[2 * t] = m;
    minv[2 * t + 1] = rsqrtf(var + 1e-5f);
  }
}

// ---- K4: per-pixel local 3x3 conv + CA partials. grid (8,4,64), 2 vertical px/thread
// part layout: [row=128][ch=512], row = (by*8+bx)*4 + wave.
__global__ __launch_bounds__(256) void k_local(const float* __restrict__ kxv,
                                               const float* __restrict__ wpre,
                                               const float* __restrict__ minv,
                                               const float* __restrict__ gnw,
                                               const float* __restrict__ gnb,
                                               float* __restrict__ out,
                                               float* __restrict__ part) {
  __shared__ float xt[8][34][24];
  const int tid = threadIdx.x;
  const int tx = tid & 15, ty = tid >> 4;
  const int z = blockIdx.z;
  const int b2 = z >> 2, g = z & 3;
  const int t = b2 & 1, b = b2 >> 1;
  const int h0 = blockIdx.y * 32, w0 = blockIdx.x * 16;
  for (int i = tid; i < 8 * 612; i += 256) {
    int ch = i / 612, r = i - ch * 612;
    int yy = r / 18, xx = r - yy * 18;
    int gh = h0 + yy - 1, gw = w0 + xx - 1;
    float v = 0.f;
    if (gh >= 0 && gh < Hd && gw >= 0 && gw < Wd)
      v = kxv[((long)(b2 * 32 + g * 8 + ch) << 14) + (gh << 7) + gw];
    xt[ch][yy][xx] = v;
  }
  __syncthreads();
  const int gg = 4 * t + g;
  const float m = minv[(b * 8 + gg) * 2];
  const float inv = minv[(b * 8 + gg) * 2 + 1];
  const int p0 = ((h0 + 2 * ty) << 7) + (w0 + tx);
  const int p1 = p0 + 128;
  float wn0[9], wn1[9];
  #pragma unroll
  for (int kk = 0; kk < 9; ++kk) {
    const int ch72 = 36 * t + 9 * g + kk;
    const long base = ((long)(b * 72 + ch72) << 14);
    const float sc = inv * gnw[ch72], sh = gnb[ch72] - m * inv * gnw[ch72];
    wn0[kk] = wpre[base + p0] * sc + sh;
    wn1[kk] = wpre[base + p1] * sc + sh;
  }
  const int prow = (blockIdx.y * 8 + blockIdx.x) * 4 + (tid >> 6);
  #pragma unroll
  for (int cc = 0; cc < 8; ++cc) {
    float nb[12];
    #pragma unroll
    for (int rr = 0; rr < 4; ++rr)
      #pragma unroll
      for (int ccol = 0; ccol < 3; ++ccol)
        nb[rr * 3 + ccol] = xt[cc][2 * ty + rr][tx + ccol];
    float o0 = 0.f, o1 = 0.f;
    #pragma unroll
    for (int dy = 0; dy < 3; ++dy)
      #pragma unroll
      for (int dx = 0; dx < 3; ++dx) {
        o0 += wn0[dy * 3 + dx] * nb[dy * 3 + dx];
        o1 += wn1[dy * 3 + dx] * nb[(dy + 1) * 3 + dx];
      }
    const int ch512 = b2 * 32 + g * 8 + cc;
    out[((long)ch512 << 14) + p0] = o0;
    out[((long)ch512 << 14) + p1] = o1;
    float os = wred(o0 + o1);
    if ((tid & 63) == 0) part[prow * 512 + ch512] = os;
  }
}

// ---- K5: reduce CA partials + SE MLP (64 -> 4 relu -> 64 sigmoid). 1 block x 512 ----
__global__ void k_ca(const float* __restrict__ part, const float* __restrict__ du1,
                     const float* __restrict__ du2, float* __restrict__ ys) {
  __shared__ float sy[8][64];
  __shared__ float sy4[8][4];
  const int tid = threadIdx.x;  // 512
  const int b = tid >> 6, c = tid & 63;
  float acc = 0.f;
  #pragma unroll 8
  for (int r = 0; r < 128; ++r) acc += part[r * 512 + tid];
  sy[b][c] = acc * (1.f / (float)HW);
  __syncthreads();
  if (tid < 32) {
    int bb = tid >> 2, j = tid & 3;
    float a = 0.f;
    for (int c2 = 0; c2 < 64; ++c2) a += sy[bb][c2] * du1[j * 64 + c2];
    sy4[bb][j] = fmaxf(a, 0.f);
  }
  __syncthreads();
  float z = 0.f;
  #pragma unroll
  for (int j = 0; j < 4; ++j) z += sy4[b][j] * du2[c * 4 + j];
  ys[tid] = 1.f / (1.f + expf(-z));
}

// ---- K6: scale output by channel-attention gate ----
__global__ __launch_bounds__(256) void k_scale(float* __restrict__ out,
                                               const float* __restrict__ ys) {
  const long i4 = (long)blockIdx.x * 256 + threadIdx.x;  // float4 index
  const long e = i4 * 4;
  const int bc = (int)(e >> 14);  // b*64+c
  const float s = ys[bc];
  float4* o = (float4*)out;
  float4 v = o[i4];
  v.x *= s; v.y *= s; v.z *= s; v.w *= s;
  o[i4] = v;
}

extern "C" void kernel_launch(void* const* d_in, const int* in_sizes, int n_in,
                              void* d_out, int out_size, void* d_ws, size_t ws_size,
                              hipStream_t stream) {
  const float* x    = (const float*)d_in[0];
  const float* wkey = (const float*)d_in[1];
  const float* we1  = (const float*)d_in[2];
  const float* we2  = (const float*)d_in[3];
  const float* be2  = (const float*)d_in[4];
  const float* gnw  = (const float*)d_in[5];
  const float* gnb  = (const float*)d_in[6];
  const float* wc1  = (const float*)d_in[7];
  const float* du1  = (const float*)d_in[8];
  const float* du2  = (const float*)d_in[9];
  float* out = (float*)d_out;
  float* ws = (float*)d_ws;

  float* kxv  = ws;                    // 8*64*HW floats (k, then xv in place)
  float* wpre = ws + 8388608;          // 8*72*HW floats
  float* part = ws + 17825792;         // spart [128][128] / part [128][512] overlay
  float* spart = part;                 //   (disjoint lifetimes)
  float* minv = part + 131072;         // 128 floats
  float* ys   = minv + 128;            // 512 floats

  k_keyconv<<<dim3(8, 4, 64), 256, 0, stream>>>(x, wkey, kxv);
  k_embed<<<dim3(32, 8, 2), 256, 0, stream>>>(x, kxv, we1, we2, be2, wc1, wpre, spart);
  k_gnstat<<<1, 128, 0, stream>>>(spart, minv);
  k_local<<<dim3(8, 4, 64), 256, 0, stream>>>(kxv, wpre, minv, gnw, gnb, out, part);
  k_ca<<<1, 512, 0, stream>>>(part, du1, du2, ys);
  k_scale<<<8192, 256, 0, stream>>>(out, ys);
}

// Round 6
// 243.107 us; speedup vs baseline: 1.1762x; 1.1726x over previous
//
#include <hip/hip_runtime.h>
#include <math.h>

#define Hd 128
#define Wd 128
#define HW 16384

__device__ __forceinline__ float wred(float v) {
  #pragma unroll
  for (int o = 32; o > 0; o >>= 1) v += __shfl_down(v, o, 64);
  return v;
}

// ---- K1: grouped 3x3 key conv + ReLU. grid (8,4,64), block 256; 2 vertical px/thread
// z = b*8+g. Tile 16w x 32h, halo 34x18 in LDS rows padded to 24 (exact 2-way banks).
__global__ __launch_bounds__(256) void k_keyconv(const float* __restrict__ x,
                                                 const float* __restrict__ wkey,
                                                 float* __restrict__ kout) {
  __shared__ float xt[8][34][24];
  const int tid = threadIdx.x;
  const int tx = tid & 15, ty = tid >> 4;  // ty 0..15 -> rows 2ty, 2ty+1
  const int b = blockIdx.z >> 3, g = blockIdx.z & 7;
  const int h0 = blockIdx.y * 32, w0 = blockIdx.x * 16;
  for (int i = tid; i < 8 * 612; i += 256) {
    int ch = i / 612, r = i - ch * 612;
    int yy = r / 18, xx = r - yy * 18;
    int gh = h0 + yy - 1, gw = w0 + xx - 1;
    float v = 0.f;
    if (gh >= 0 && gh < Hd && gw >= 0 && gw < Wd)
      v = x[((long)(b * 64 + g * 8 + ch) << 14) + (gh << 7) + gw];
    xt[ch][yy][xx] = v;
  }
  __syncthreads();
  float acc0[8] = {0.f, 0.f, 0.f, 0.f, 0.f, 0.f, 0.f, 0.f};
  float acc1[8] = {0.f, 0.f, 0.f, 0.f, 0.f, 0.f, 0.f, 0.f};
  const float* wg = wkey + g * 576;
  #pragma unroll
  for (int ich = 0; ich < 8; ++ich) {
    float nb[12];  // input rows 2ty-1 .. 2ty+2 -> xt rows 2ty..2ty+3, cols tx..tx+2
    #pragma unroll
    for (int rr = 0; rr < 4; ++rr)
      #pragma unroll
      for (int cc = 0; cc < 3; ++cc)
        nb[rr * 3 + cc] = xt[ich][2 * ty + rr][tx + cc];
    #pragma unroll
    for (int oc = 0; oc < 8; ++oc) {
      const float* wr = wg + oc * 72 + ich * 9;  // wave-uniform -> scalar loads
      #pragma unroll
      for (int dy = 0; dy < 3; ++dy)
        #pragma unroll
        for (int dx = 0; dx < 3; ++dx) {
          float wv = wr[dy * 3 + dx];
          acc0[oc] += wv * nb[dy * 3 + dx];
          acc1[oc] += wv * nb[(dy + 1) * 3 + dx];
        }
    }
  }
  const int h = h0 + 2 * ty, w = w0 + tx;
  #pragma unroll
  for (int oc = 0; oc < 8; ++oc) {
    const long base = ((long)(b * 64 + g * 8 + oc) << 14);
    kout[base + (h << 7) + w] = fmaxf(acc0[oc], 0.f);
    kout[base + ((h + 1) << 7) + w] = fmaxf(acc1[oc], 0.f);
  }
}

// ---- K2: pointwise e1+e2 + c1 + GN partials (R3 structure: 1 px/thread, thin waves)
// grid (128, B, 2), block 128 (2 waves). z = s. xv overwrites k in place
// (same-thread read->write, same pointer => program order preserved).
// spart layout: [row=256][col=128], row = bx*2 + wave.
__global__ __launch_bounds__(128) void k_embed(const float* __restrict__ x,
                                               float* __restrict__ kxv,
                                               const float* __restrict__ we1,
                                               const float* __restrict__ we2,
                                               const float* __restrict__ be2,
                                               const float* __restrict__ wc1,
                                               float* __restrict__ wpre,
                                               float* __restrict__ spart) {
  const int tid = threadIdx.x;
  const int p = blockIdx.x * 128 + tid;
  const int b = blockIdx.y;
  const int s = blockIdx.z;
  float xc[32], kc[32];
  #pragma unroll
  for (int j = 0; j < 32; ++j) {
    xc[j] = x[((long)(b * 64 + 32 * s + j) << 14) + p];
    kc[j] = kxv[((long)(b * 64 + 32 * s + j) << 14) + p];
  }
  // value path: grouped 1x1 conv (32->32 per half), store xv over k slots
  #pragma unroll 4
  for (int o = 0; o < 32; ++o) {
    const float* wr = wc1 + (32 * s + o) * 32;
    float a = 0.f;
    #pragma unroll
    for (int j = 0; j < 32; ++j) a += wr[j] * xc[j];
    kxv[((long)(b * 64 + 32 * s + o) << 14) + p] = a;
  }
  // e1: 64(interleaved x,k) -> 16, ReLU
  float w1a[16];
  #pragma unroll
  for (int o = 0; o < 16; ++o) {
    const float* wr = we1 + (16 * s + o) * 64;
    float a = 0.f;
    #pragma unroll
    for (int j = 0; j < 32; ++j) a += wr[2 * j] * xc[j] + wr[2 * j + 1] * kc[j];
    w1a[o] = fmaxf(a, 0.f);
  }
  // e2: 16 -> 36 (+bias), store w_pre, per-wave GN sum/sumsq -> spart slot
  const int row = blockIdx.x * 2 + (tid >> 6);
  #pragma unroll
  for (int gl = 0; gl < 4; ++gl) {
    float lgs = 0.f, lgq = 0.f;
    #pragma unroll
    for (int kk = 0; kk < 9; ++kk) {
      const int oc2 = 36 * s + gl * 9 + kk;
      const float* wr = we2 + oc2 * 16;
      float a = be2[oc2];
      #pragma unroll
      for (int ic = 0; ic < 16; ++ic) a += wr[ic] * w1a[ic];
      wpre[((long)(b * 72 + oc2) << 14) + p] = a;
      lgs += a;
      lgq += a * a;
    }
    float r1 = wred(lgs), r2 = wred(lgq);
    if ((tid & 63) == 0) {
      spart[row * 128 + (b * 8 + 4 * s + gl) * 2 + 0] = r1;
      spart[row * 128 + (b * 8 + 4 * s + gl) * 2 + 1] = r2;
    }
  }
}

// ---- K3: reduce spart columns + finalize GN stats. 1 block x 128 threads ----
__global__ void k_gnstat(const float* __restrict__ spart, float* __restrict__ minv) {
  __shared__ float sred[128];
  const int t = threadIdx.x;  // 128
  float a = 0.f;
  #pragma unroll 8
  for (int r = 0; r < 256; ++r) a += spart[r * 128 + t];
  sred[t] = a;
  __syncthreads();
  if (t < 64) {
    const float N = 9.f * (float)HW;
    float s = sred[2 * t], q = sred[2 * t + 1];
    float m = s / N;
    float var = q / N - m * m;
    minv[2 * t] = m;
    minv[2 * t + 1] = rsqrtf(var + 1e-5f);
  }
}

// ---- K4: per-pixel local 3x3 conv + CA partials. grid (8,4,64), 2 vertical px/thread
// part layout: [row=128][ch=512], row = (by*8+bx)*4 + wave.
__global__ __launch_bounds__(256) void k_local(const float* __restrict__ kxv,
                                               const float* __restrict__ wpre,
                                               const float* __restrict__ minv,
                                               const float* __restrict__ gnw,
                                               const float* __restrict__ gnb,
                                               float* __restrict__ out,
                                               float* __restrict__ part) {
  __shared__ float xt[8][34][24];
  const int tid = threadIdx.x;
  const int tx = tid & 15, ty = tid >> 4;
  const int z = blockIdx.z;
  const int b2 = z >> 2, g = z & 3;
  const int t = b2 & 1, b = b2 >> 1;
  const int h0 = blockIdx.y * 32, w0 = blockIdx.x * 16;
  for (int i = tid; i < 8 * 612; i += 256) {
    int ch = i / 612, r = i - ch * 612;
    int yy = r / 18, xx = r - yy * 18;
    int gh = h0 + yy - 1, gw = w0 + xx - 1;
    float v = 0.f;
    if (gh >= 0 && gh < Hd && gw >= 0 && gw < Wd)
      v = kxv[((long)(b2 * 32 + g * 8 + ch) << 14) + (gh << 7) + gw];
    xt[ch][yy][xx] = v;
  }
  __syncthreads();
  const int gg = 4 * t + g;
  const float m = minv[(b * 8 + gg) * 2];
  const float inv = minv[(b * 8 + gg) * 2 + 1];
  const int p0 = ((h0 + 2 * ty) << 7) + (w0 + tx);
  const int p1 = p0 + 128;
  float wn0[9], wn1[9];
  #pragma unroll
  for (int kk = 0; kk < 9; ++kk) {
    const int ch72 = 36 * t + 9 * g + kk;
    const long base = ((long)(b * 72 + ch72) << 14);
    const float sc = inv * gnw[ch72], sh = gnb[ch72] - m * inv * gnw[ch72];
    wn0[kk] = wpre[base + p0] * sc + sh;
    wn1[kk] = wpre[base + p1] * sc + sh;
  }
  const int prow = (blockIdx.y * 8 + blockIdx.x) * 4 + (tid >> 6);
  #pragma unroll
  for (int cc = 0; cc < 8; ++cc) {
    float nb[12];
    #pragma unroll
    for (int rr = 0; rr < 4; ++rr)
      #pragma unroll
      for (int ccol = 0; ccol < 3; ++ccol)
        nb[rr * 3 + ccol] = xt[cc][2 * ty + rr][tx + ccol];
    float o0 = 0.f, o1 = 0.f;
    #pragma unroll
    for (int dy = 0; dy < 3; ++dy)
      #pragma unroll
      for (int dx = 0; dx < 3; ++dx) {
        o0 += wn0[dy * 3 + dx] * nb[dy * 3 + dx];
        o1 += wn1[dy * 3 + dx] * nb[(dy + 1) * 3 + dx];
      }
    const int ch512 = b2 * 32 + g * 8 + cc;
    out[((long)ch512 << 14) + p0] = o0;
    out[((long)ch512 << 14) + p1] = o1;
    float os = wred(o0 + o1);
    if ((tid & 63) == 0) part[prow * 512 + ch512] = os;
  }
}

// ---- K5: reduce CA partials + SE MLP (64 -> 4 relu -> 64 sigmoid). 1 block x 512 ----
__global__ void k_ca(const float* __restrict__ part, const float* __restrict__ du1,
                     const float* __restrict__ du2, float* __restrict__ ys) {
  __shared__ float sy[8][64];
  __shared__ float sy4[8][4];
  const int tid = threadIdx.x;  // 512
  const int b = tid >> 6, c = tid & 63;
  float acc = 0.f;
  #pragma unroll 8
  for (int r = 0; r < 128; ++r) acc += part[r * 512 + tid];
  sy[b][c] = acc * (1.f / (float)HW);
  __syncthreads();
  if (tid < 32) {
    int bb = tid >> 2, j = tid & 3;
    float a = 0.f;
    for (int c2 = 0; c2 < 64; ++c2) a += sy[bb][c2] * du1[j * 64 + c2];
    sy4[bb][j] = fmaxf(a, 0.f);
  }
  __syncthreads();
  float z = 0.f;
  #pragma unroll
  for (int j = 0; j < 4; ++j) z += sy4[b][j] * du2[c * 4 + j];
  ys[tid] = 1.f / (1.f + expf(-z));
}

// ---- K6: scale output by channel-attention gate ----
__global__ __launch_bounds__(256) void k_scale(float* __restrict__ out,
                                               const float* __restrict__ ys) {
  const long i4 = (long)blockIdx.x * 256 + threadIdx.x;  // float4 index
  const long e = i4 * 4;
  const int bc = (int)(e >> 14);  // b*64+c
  const float s = ys[bc];
  float4* o = (float4*)out;
  float4 v = o[i4];
  v.x *= s; v.y *= s; v.z *= s; v.w *= s;
  o[i4] = v;
}

extern "C" void kernel_launch(void* const* d_in, const int* in_sizes, int n_in,
                              void* d_out, int out_size, void* d_ws, size_t ws_size,
                              hipStream_t stream) {
  const float* x    = (const float*)d_in[0];
  const float* wkey = (const float*)d_in[1];
  const float* we1  = (const float*)d_in[2];
  const float* we2  = (const float*)d_in[3];
  const float* be2  = (const float*)d_in[4];
  const float* gnw  = (const float*)d_in[5];
  const float* gnb  = (const float*)d_in[6];
  const float* wc1  = (const float*)d_in[7];
  const float* du1  = (const float*)d_in[8];
  const float* du2  = (const float*)d_in[9];
  float* out = (float*)d_out;
  float* ws = (float*)d_ws;

  float* kxv  = ws;                    // 8*64*HW floats (k, then xv in place)
  float* wpre = ws + 8388608;          // 8*72*HW floats
  float* part = ws + 17825792;         // spart [256][128] / part [128][512] overlay
  float* spart = part;                 //   (disjoint lifetimes)
  float* minv = part + 131072;         // 128 floats
  float* ys   = minv + 128;            // 512 floats

  k_keyconv<<<dim3(8, 4, 64), 256, 0, stream>>>(x, wkey, kxv);
  k_embed<<<dim3(128, 8, 2), 128, 0, stream>>>(x, kxv, we1, we2, be2, wc1, wpre, spart);
  k_gnstat<<<1, 128, 0, stream>>>(spart, minv);
  k_local<<<dim3(8, 4, 64), 256, 0, stream>>>(kxv, wpre, minv, gnw, gnb, out, part);
  k_ca<<<1, 512, 0, stream>>>(part, du1, du2, ys);
  k_scale<<<8192, 256, 0, stream>>>(out, ys);
}